// Round 7
// baseline (107.500 us; speedup 1.0000x reference)
//
#include <hip/hip_runtime.h>
#include <hip/hip_fp16.h>
#include <math.h>

#define F_CNT 1024
#define H_IMG 192
#define W_IMG 192
#define HW (H_IMG * W_IMG)
#define EPSF 1e-8f
#define N_SEG 8
#define SEG_LEN 128
#define HALF_PX 72
#define PIX_PER_BLK 144
#define LOG2E 1.4426950408889634f

#define RCP(x) __builtin_amdgcn_rcpf(x)

// R7: break the hot-wave latency chain. R5==R6 proved the render wall is
// the per-iteration dependent LDS chain (hlist -> record -> blend, ~300cyc
// unpipelined), invariant to CU placement. Fix: (1) cull maps lane l ->
// records {l, l+64} so the ballot masks enumerate hits in ascending record
// order -- next-index comes from ctz on wave-uniform registers, no LDS;
// (2) depth-2 software prefetch of record float4s into named registers.
// Hit set and blend order unchanged -> bit-identical output.
// kernel1 (prep+sort) and kernel3 (combine) verbatim from passing R6.

// ---------------------------------------------------------------- kernel 1
__global__ __launch_bounds__(1024)
void prep_sort_kernel(const float* __restrict__ vp,
                      const int*   __restrict__ faces,
                      const float* __restrict__ rot_qs,
                      const float* __restrict__ log_scales,
                      const float* __restrict__ colors,
                      const float* __restrict__ log_opac,
                      float* __restrict__ params,
                      float* __restrict__ out)
{
    __shared__ float sp[8][F_CNT];
    __shared__ unsigned long long skv[F_CNT];

    const int f = threadIdx.x;
    if (f == 0) out[3 * HW] = 0.0f;   // zero the loss accumulator slot

    const int ia = faces[3 * f + 0], ib = faces[3 * f + 1], ic = faces[3 * f + 2];
    const float Ax = vp[3 * ia + 0], Ay = vp[3 * ia + 1], Az = vp[3 * ia + 2];
    const float Bx = vp[3 * ib + 0], By = vp[3 * ib + 1], Bz = vp[3 * ib + 2];
    const float Cx = vp[3 * ic + 0], Cy = vp[3 * ic + 1], Cz = vp[3 * ic + 2];

    // ---- sort-key chain: EXACT IEEE (do not touch) ----
    const float tx = (Ax + Bx + Cx) / 3.0f;
    const float ty = (Ay + By + Cy) / 3.0f;
    const float tz = (Az + Bz + Cz) / 3.0f;

    const float e1x = Bx - Ax, e1y = By - Ay, e1z = Bz - Az;
    const float e2x = Cx - Ax, e2y = Cy - Ay, e2z = Cz - Az;

    const float rn1 = RCP(sqrtf(e1x * e1x + e1y * e1y + e1z * e1z) + EPSF);
    const float ux = e1x * rn1, uy = e1y * rn1, uz = e1z * rn1;
    const float cnx = e1y * e2z - e1z * e2y;
    const float cny = e1z * e2x - e1x * e2z;
    const float cnz = e1x * e2y - e1y * e2x;
    const float rn2 = RCP(sqrtf(cnx * cnx + cny * cny + cnz * cnz) + EPSF);
    const float wxv = cnx * rn2, wyv = cny * rn2, wzv = cnz * rn2;
    const float vx = wyv * uz - wzv * uy;
    const float vy = wzv * ux - wxv * uz;
    const float vz = wxv * uy - wyv * ux;

    const float q0 = rot_qs[4 * f + 0], q1 = rot_qs[4 * f + 1];
    const float q2 = rot_qs[4 * f + 2], q3 = rot_qs[4 * f + 3];
    const float rqn = RCP(sqrtf(q0 * q0 + q1 * q1 + q2 * q2 + q3 * q3) + EPSF);
    const float qw = q0 * rqn, qx = q1 * rqn, qy = q2 * rqn, qz = q3 * rqn;
    const float R00 = 1.0f - 2.0f * (qy * qy + qz * qz);
    const float R01 = 2.0f * (qx * qy - qw * qz);
    const float R02 = 2.0f * (qx * qz + qw * qy);
    const float R10 = 2.0f * (qx * qy + qw * qz);
    const float R11 = 1.0f - 2.0f * (qx * qx + qz * qz);
    const float R12 = 2.0f * (qy * qz - qw * qx);
    const float R20 = 2.0f * (qx * qz - qw * qy);
    const float R21 = 2.0f * (qy * qz + qw * qx);
    const float R22 = 1.0f - 2.0f * (qx * qx + qy * qy);

    const float s0 = expf(log_scales[3 * f + 0]);
    const float s1 = expf(log_scales[3 * f + 1]);
    const float s2 = expf(log_scales[3 * f + 2]);

    float G00, G10, G20, G01, G11, G21, G02, G12, G22;
    {
        float c0 = s0 * R00, c1 = s1 * R01, c2 = s2 * R02;
        G00 = ux * c0 + vx * c1 + wxv * c2;
        G10 = uy * c0 + vy * c1 + wyv * c2;
        G20 = uz * c0 + vz * c1 + wzv * c2;
    }
    {
        float c0 = s0 * R10, c1 = s1 * R11, c2 = s2 * R12;
        G01 = ux * c0 + vx * c1 + wxv * c2;
        G11 = uy * c0 + vy * c1 + wyv * c2;
        G21 = uz * c0 + vz * c1 + wzv * c2;
    }
    {
        float c0 = s0 * R20, c1 = s1 * R21, c2 = s2 * R22;
        G02 = ux * c0 + vx * c1 + wxv * c2;
        G12 = uy * c0 + vy * c1 + wyv * c2;
        G22 = uz * c0 + vz * c1 + wzv * c2;
    }

    const float gs0 = sqrtf(G00 * G00 + G10 * G10 + G20 * G20);
    const float gs1 = sqrtf(G01 * G01 + G11 * G11 + G21 * G21);
    const float gs2 = sqrtf(G02 * G02 + G12 * G12 + G22 * G22);
    const float rd0 = RCP(gs0 + EPSF), rd1 = RCP(gs1 + EPSF), rd2 = RCP(gs2 + EPSF);
    const float r00 = G00 * rd0, r10 = G10 * rd0, r20 = G20 * rd0;
    const float r01 = G01 * rd1, r11 = G11 * rd1, r21 = G21 * rd1;
    const float r02 = G02 * rd2, r12 = G12 * rd2, r22 = G22 * rd2;

    const float Qw = 0.5f * sqrtf(fmaxf(EPSF, 1.0f + r00 + r11 + r22));
    const float Qx = copysignf(0.5f * sqrtf(fmaxf(EPSF, 1.0f + r00 - r11 - r22)), r21 - r12);
    const float Qy = copysignf(0.5f * sqrtf(fmaxf(EPSF, 1.0f - r00 + r11 - r22)), r02 - r20);
    const float Qz = copysignf(0.5f * sqrtf(fmaxf(EPSF, 1.0f - r00 - r11 + r22)), r10 - r01);

    const float rqn2 = RCP(sqrtf(Qw * Qw + Qx * Qx + Qy * Qy + Qz * Qz) + EPSF);
    const float pw = Qw * rqn2, px = Qx * rqn2, py = Qy * rqn2, pz = Qz * rqn2;
    const float N00 = 1.0f - 2.0f * (py * py + pz * pz);
    const float N01 = 2.0f * (px * py - pw * pz);
    const float N02 = 2.0f * (px * pz + pw * py);
    const float N10 = 2.0f * (px * py + pw * pz);
    const float N11 = 1.0f - 2.0f * (px * px + pz * pz);
    const float N12 = 2.0f * (py * pz - pw * px);
    const float N20 = 2.0f * (px * pz - pw * py);
    const float N21 = 2.0f * (py * pz + pw * px);
    const float N22 = 1.0f - 2.0f * (px * px + py * py);

    const float M00 = N00 * gs0, M01 = N01 * gs1, M02 = N02 * gs2;
    const float M10 = N10 * gs0, M11 = N11 * gs1, M12 = N12 * gs2;
    const float M20 = N20 * gs0, M21 = N21 * gs1, M22 = N22 * gs2;
    const float C00 = M00 * M00 + M01 * M01 + M02 * M02;
    const float C01 = M00 * M10 + M01 * M11 + M02 * M12;
    const float C02 = M00 * M20 + M01 * M21 + M02 * M22;
    const float C11 = M10 * M10 + M11 * M11 + M12 * M12;
    const float C12 = M10 * M20 + M11 * M21 + M12 * M22;
    const float C22 = M20 * M20 + M21 * M21 + M22 * M22;

    const float valid = (tz > 0.2f) ? 1.0f : 0.0f;
    const float Zc = fmaxf(tz, 0.2f);           // sort key: exact
    const float rZc = RCP(Zc);
    const float mx = 200.0f * tx * rZc + 96.0f;
    const float my = 200.0f * ty * rZc + 96.0f;
    const float j00 = 200.0f * rZc;
    const float j02 = -200.0f * tx * (rZc * rZc);
    const float j11 = 200.0f * rZc;
    const float j12 = -200.0f * ty * (rZc * rZc);
    const float v00 = j00 * j00 * C00 + 2.0f * j00 * j02 * C02 + j02 * j02 * C22 + 0.3f;
    const float v01 = j00 * j11 * C01 + j00 * j12 * C02 + j02 * j11 * C12 + j02 * j12 * C22;
    const float v11 = j11 * j11 * C11 + 2.0f * j11 * j12 * C12 + j12 * j12 * C22 + 0.3f;
    const float rdet = RCP(fmaxf(v00 * v11 - v01 * v01, EPSF));
    const float conA = v11 * rdet, conB = -v01 * rdet, conC = v00 * rdet;
    const float opv = expf(log_opac[f]) * valid;

    const float LA = 0.5f * LOG2E * conA;
    const float LB = LOG2E * conB;
    const float LC = 0.5f * LOG2E * conC;
    const float t4 = fmaf(-LB, LB, 4.0f * LA * LC);
    const float reach2 = 140.0f * LA * RCP(fmaxf(t4, 1e-30f));

    union { __half2 h; float f; } c01u, cbo;
    c01u.h = __floats2half2_rn(colors[3 * f + 0], colors[3 * f + 1]);
    cbo.h  = __floats2half2_rn(colors[3 * f + 2], opv);

    sp[0][f] = mx;
    sp[1][f] = my;
    sp[2][f] = reach2;
    sp[3][f] = LA;
    sp[4][f] = LB;
    sp[5][f] = LC;
    sp[6][f] = c01u.f;
    sp[7][f] = cbo.f;

    // ---- bitonic argsort on packed u64 (proven R1 network) ----
    unsigned long long kv =
        ((unsigned long long)__float_as_uint(Zc) << 32) | (unsigned int)f;

    #pragma unroll
    for (int k = 2; k <= 64; k <<= 1)
        #pragma unroll
        for (int j = k >> 1; j > 0; j >>= 1) {
            const unsigned long long pk = __shfl_xor(kv, j, 64);
            const bool keep_min = (((f & k) == 0) == ((f & j) == 0));
            kv = ((pk < kv) == keep_min) ? pk : kv;
        }

    skv[f] = kv;
    __syncthreads();

    for (int k = 128; k <= F_CNT; k <<= 1) {
        for (int j = k >> 1; j >= 64; j >>= 1) {
            const int x = f ^ j;
            if (x > f) {
                const unsigned long long a  = skv[f];
                const unsigned long long bb = skv[x];
                const bool up = ((f & k) == 0);
                if (up ? (a > bb) : (a < bb)) { skv[f] = bb; skv[x] = a; }
            }
            __syncthreads();
        }
        kv = skv[f];
        #pragma unroll
        for (int j = 32; j > 0; j >>= 1) {
            const unsigned long long pk = __shfl_xor(kv, j, 64);
            const bool keep_min = (((f & k) == 0) == ((f & j) == 0));
            kv = ((pk < kv) == keep_min) ? pk : kv;
        }
        skv[f] = kv;
        __syncthreads();
    }

    // ---- gather-write sorted 32 B records ----
    const int src = (int)(skv[f] & 0xffffffffULL);
    float4* __restrict__ d4 = (float4*)params + 2 * f;
    d4[0] = make_float4(sp[0][src], sp[1][src], sp[2][src], sp[3][src]);
    d4[1] = make_float4(sp[4][src], sp[5][src], sp[6][src], sp[7][src]);
}

// ---------------------------------------------------------------- kernel 2
// 512 blocks: h = bid>>8 picks segment half [4h,4h+4); region r =
// (bid + h*128) & 255. 8 waves = 4 local segs x 2 strips. Cull: lane l
// tests records l and l+64 of its segment -> ballot masks mA (records
// 0-63) and mB (64-127) enumerate hits in ascending record order via ctz.
// Blend loop walks the masks (register-only next-index) with depth-2
// prefetch of the record float4s. Hit set + blend order == R6 -> bit-exact.
__global__ __launch_bounds__(512)
void render_partial_kernel(const float* __restrict__ params,
                           float* __restrict__ partials)
{
    __shared__ float4 lds4[1024];          // 512 records x 2 float4 = 16 KB
    __shared__ float2 myr[512];            // (my, reach2) side table, 4 KB

    const int tid  = threadIdx.x;
    const int lane = tid & 63;
    const int wv   = tid >> 6;             // 0..7

    const int bid = blockIdx.x;
    const int h   = bid >> 8;              // segment half
    const int r   = (bid + (h ? 128 : 0)) & 255;   // pixel region

    // ---- stage this half's 512 records ----
    {
        const float4* __restrict__ rec4 = (const float4*)params;
        const float4 a  = rec4[2 * (512 * h + tid) + 0];
        const float4 bb = rec4[2 * (512 * h + tid) + 1];
        lds4[2 * tid + 0] = a;
        lds4[2 * tid + 1] = bb;
        myr[tid] = make_float2(a.y, a.z);
    }
    __syncthreads();

    const int pb1 = r * HALF_PX;
    const int pb2 = HW / 2 + r * HALF_PX;
    const int seg_l  = wv & 3;
    const bool strip2 = (wv >= 4);
    const int pbase  = strip2 ? pb2 : pb1;

    const float ra = (float)(pbase / W_IMG);
    const float rb = (float)((pbase + HALF_PX - 1) / W_IMG);

    // ---- wave-parallel cull: lane l -> records l, l+64 ----
    unsigned long long mA, mB;
    {
        const float2 t0 = myr[seg_l * 128 + lane];        // record lane
        const float2 t1 = myr[seg_l * 128 + 64 + lane];   // record lane+64
        const float dm0 = fmaxf(0.0f, fmaxf(ra - t0.x, t0.x - rb));
        const float dm1 = fmaxf(0.0f, fmaxf(ra - t1.x, t1.x - rb));
        const bool h0 = dm0 * dm0 <= t0.y;
        const bool h1 = dm1 * dm1 <= t1.y;
        mA = __ballot(h0);   // bit l <-> record l     (ascending)
        mB = __ballot(h1);   // bit l <-> record l+64  (ascending)
    }

    const int p0 = pbase + lane, p1 = pbase + 64 + lane;
    const float fx0 = (float)(p0 % W_IMG), fy0 = (float)(p0 / W_IMG);
    const float fx1 = (float)(p1 % W_IMG), fy1 = (float)(p1 / W_IMG);

    float T0 = 1.0f, R0 = 0.0f, G0 = 0.0f, B0 = 0.0f;
    float T1 = 1.0f, R1 = 0.0f, G1 = 0.0f, B1 = 0.0f;

    // ---- mask-walk blend with depth-2 record prefetch ----
    // NEXT_R: wave-uniform (masks identical across lanes) -> scalar branches.
    const float4* __restrict__ Lb = lds4 + (seg_l << 7) * 2;  // seg_l*128 records
    unsigned long long mm = mA;
    bool ph2 = false;

#define NEXT_R(dst) do {                                              \
        if (mm == 0ULL && !ph2) { mm = mB; ph2 = true; }              \
        if (mm != 0ULL) {                                             \
            const int _b = (int)__builtin_ctzll(mm);                  \
            mm &= mm - 1ULL;                                          \
            (dst) = _b + (ph2 ? 64 : 0);                              \
        } else (dst) = -1;                                            \
    } while (0)

    int rA, rB;
    NEXT_R(rA);
    rB = -1;
    float4 aP0, bP0, aP1, bP1;
    if (rA >= 0) {
        aP0 = Lb[2 * rA + 0]; bP0 = Lb[2 * rA + 1];
        NEXT_R(rB);
        if (rB >= 0) { aP1 = Lb[2 * rB + 0]; bP1 = Lb[2 * rB + 1]; }
    }

    while (rA >= 0) {
        const float4 a  = aP0;
        const float4 bb = bP0;
        // rotate pipeline and issue prefetch for 2-ahead
        aP0 = aP1; bP0 = bP1;
        int rN = -1;
        if (rB >= 0) NEXT_R(rN);
        if (rN >= 0) { aP1 = Lb[2 * rN + 0]; bP1 = Lb[2 * rN + 1]; }

        const float my = a.y;
        const float LA = a.w, LB = bb.x, LC = bb.y;
        union { float f; __half2 h; } urg, ubo;
        urg.f = bb.z;  ubo.f = bb.w;
        const float2 crg = __half22float2(urg.h);
        const float2 cbo = __half22float2(ubo.h);
        const float  cb  = cbo.x, opv = cbo.y;

        {
            const float dx = fx0 - a.x, dy = fy0 - my;
            const float t  = fmaf(LB, dy, LA * dx);
            const float u2 = (LC * dy) * dy;
            const float n  = -fmaf(t, dx, u2);
            const float e2 = exp2f(fminf(n, 0.0f));
            const float al = fminf(opv * e2, 0.99f);
            const float w  = al * T0;
            R0 = fmaf(w, crg.x, R0); G0 = fmaf(w, crg.y, G0); B0 = fmaf(w, cb, B0);
            T0 -= w;
        }
        {
            const float dx = fx1 - a.x, dy = fy1 - my;
            const float t  = fmaf(LB, dy, LA * dx);
            const float u2 = (LC * dy) * dy;
            const float n  = -fmaf(t, dx, u2);
            const float e2 = exp2f(fminf(n, 0.0f));
            const float al = fminf(opv * e2, 0.99f);
            const float w  = al * T1;
            R1 = fmaf(w, crg.x, R1); G1 = fmaf(w, crg.y, G1); B1 = fmaf(w, cb, B1);
            T1 -= w;
        }

        rA = rB; rB = rN;
    }
#undef NEXT_R

    // ---- write per-(region, gseg) partials ----
    float4* __restrict__ part = (float4*)partials;
    const int gseg = 4 * h + seg_l;
    const int base = (r * N_SEG + gseg) * PIX_PER_BLK + (strip2 ? HALF_PX : 0);
    part[base + lane] = make_float4(R0, G0, B0, T0);
    if (lane < 8)
        part[base + 64 + lane] = make_float4(R1, G1, B1, T1);
}

// ---------------------------------------------------------------- kernel 3
__global__ __launch_bounds__(256)
void combine_kernel(const float* __restrict__ partials,
                    const float* __restrict__ img,
                    const float* __restrict__ mask,
                    float* __restrict__ out)
{
    __shared__ float lossb[PIX_PER_BLK];

    const int tid = threadIdx.x;
    const int c   = blockIdx.x;
    const int pb1 = c * HALF_PX;
    const int pb2 = HW / 2 + c * HALF_PX;

    float lsum = 0.0f;
    if (tid < PIX_PER_BLK) {
        const float4* __restrict__ part = (const float4*)partials;
        float R = 0.0f, G = 0.0f, B = 0.0f, Tt = 1.0f;
        #pragma unroll
        for (int s = 0; s < N_SEG; ++s) {
            const float4 cc = part[(c * N_SEG + s) * PIX_PER_BLK + tid];
            R += Tt * cc.x; G += Tt * cc.y; B += Tt * cc.z;
            Tt *= cc.w;
        }
        const float bg = Tt;
        const float o0 = R + bg, o1 = G + bg, o2 = B + bg;
        const int p = (tid < HALF_PX) ? (pb1 + tid) : (pb2 + tid - HALF_PX);
        out[p]          = o0;
        out[HW + p]     = o1;
        out[2 * HW + p] = o2;

        const float m = mask[p];
        const float base = 1.0f - m;
        const float e0 = o0 - (base + img[p] * m);
        const float e1 = o1 - (base + img[HW + p] * m);
        const float e2 = o2 - (base + img[2 * HW + p] * m);
        lsum = e0 * e0 + e1 * e1 + e2 * e2;
    }

    if (tid < PIX_PER_BLK) lossb[tid] = lsum;
    __syncthreads();
    if (tid < 64) {
        float s = lossb[tid] + lossb[tid + 64] + (tid < 16 ? lossb[tid + 128] : 0.0f);
        #pragma unroll
        for (int off = 32; off > 0; off >>= 1) s += __shfl_down(s, off);
        if (tid == 0)
            atomicAdd(out + 3 * HW, s * (1.0f / (float)(3 * HW)));
    }
}

extern "C" void kernel_launch(void* const* d_in, const int* in_sizes, int n_in,
                              void* d_out, int out_size, void* d_ws, size_t ws_size,
                              hipStream_t stream)
{
    const float* img        = (const float*)d_in[0];
    const float* mask       = (const float*)d_in[1];
    const float* vp         = (const float*)d_in[2];
    const int*   faces      = (const int*)d_in[3];
    const float* rot_qs     = (const float*)d_in[4];
    const float* log_scales = (const float*)d_in[5];
    const float* colors     = (const float*)d_in[6];
    const float* log_opac   = (const float*)d_in[7];
    float* out      = (float*)d_out;
    float* params   = (float*)d_ws;                 // 32 KB records
    float* partials = (float*)d_ws + 8192;          // 4.7 MB partials

    prep_sort_kernel<<<1, F_CNT, 0, stream>>>(vp, faces, rot_qs, log_scales,
                                              colors, log_opac, params, out);
    render_partial_kernel<<<512, 512, 0, stream>>>(params, partials);
    combine_kernel<<<256, 256, 0, stream>>>(partials, img, mask, out);
}

// Round 8
// 97.167 us; speedup vs baseline: 1.1063x; 1.1063x over previous
//
#include <hip/hip_runtime.h>
#include <hip/hip_fp16.h>
#include <math.h>

#define F_CNT 1024
#define H_IMG 192
#define W_IMG 192
#define HW (H_IMG * W_IMG)
#define EPSF 1e-8f
#define N_SEG 16                 // 16 segments x 64 records
#define SEG_LEN 64
#define HALF_PX 72
#define PIX_PER_BLK 144
#define LOG2E 1.4426950408889634f

#define RCP(x) __builtin_amdgcn_rcpf(x)

// R8: finer segmentation on the R6 base. 16 segments x 64 records:
// hot-wave serial chain halves (64 iters), grid 1024 blocks x 512 thr =
// 4 blocks/CU = 8 waves/SIMD (max occupancy; hot waves interleave with
// cold). Combine folds 16 partials (associative regroup; absmax dominated
// by half color packing, regroup noise ~1e-6). kernel1 verbatim.

// ---------------------------------------------------------------- kernel 1
__global__ __launch_bounds__(1024)
void prep_sort_kernel(const float* __restrict__ vp,
                      const int*   __restrict__ faces,
                      const float* __restrict__ rot_qs,
                      const float* __restrict__ log_scales,
                      const float* __restrict__ colors,
                      const float* __restrict__ log_opac,
                      float* __restrict__ params,
                      float* __restrict__ out)
{
    __shared__ float sp[8][F_CNT];
    __shared__ unsigned long long skv[F_CNT];

    const int f = threadIdx.x;
    if (f == 0) out[3 * HW] = 0.0f;   // zero the loss accumulator slot

    const int ia = faces[3 * f + 0], ib = faces[3 * f + 1], ic = faces[3 * f + 2];
    const float Ax = vp[3 * ia + 0], Ay = vp[3 * ia + 1], Az = vp[3 * ia + 2];
    const float Bx = vp[3 * ib + 0], By = vp[3 * ib + 1], Bz = vp[3 * ib + 2];
    const float Cx = vp[3 * ic + 0], Cy = vp[3 * ic + 1], Cz = vp[3 * ic + 2];

    // ---- sort-key chain: EXACT IEEE (do not touch) ----
    const float tx = (Ax + Bx + Cx) / 3.0f;
    const float ty = (Ay + By + Cy) / 3.0f;
    const float tz = (Az + Bz + Cz) / 3.0f;

    const float e1x = Bx - Ax, e1y = By - Ay, e1z = Bz - Az;
    const float e2x = Cx - Ax, e2y = Cy - Ay, e2z = Cz - Az;

    const float rn1 = RCP(sqrtf(e1x * e1x + e1y * e1y + e1z * e1z) + EPSF);
    const float ux = e1x * rn1, uy = e1y * rn1, uz = e1z * rn1;
    const float cnx = e1y * e2z - e1z * e2y;
    const float cny = e1z * e2x - e1x * e2z;
    const float cnz = e1x * e2y - e1y * e2x;
    const float rn2 = RCP(sqrtf(cnx * cnx + cny * cny + cnz * cnz) + EPSF);
    const float wxv = cnx * rn2, wyv = cny * rn2, wzv = cnz * rn2;
    const float vx = wyv * uz - wzv * uy;
    const float vy = wzv * ux - wxv * uz;
    const float vz = wxv * uy - wyv * ux;

    const float q0 = rot_qs[4 * f + 0], q1 = rot_qs[4 * f + 1];
    const float q2 = rot_qs[4 * f + 2], q3 = rot_qs[4 * f + 3];
    const float rqn = RCP(sqrtf(q0 * q0 + q1 * q1 + q2 * q2 + q3 * q3) + EPSF);
    const float qw = q0 * rqn, qx = q1 * rqn, qy = q2 * rqn, qz = q3 * rqn;
    const float R00 = 1.0f - 2.0f * (qy * qy + qz * qz);
    const float R01 = 2.0f * (qx * qy - qw * qz);
    const float R02 = 2.0f * (qx * qz + qw * qy);
    const float R10 = 2.0f * (qx * qy + qw * qz);
    const float R11 = 1.0f - 2.0f * (qx * qx + qz * qz);
    const float R12 = 2.0f * (qy * qz - qw * qx);
    const float R20 = 2.0f * (qx * qz - qw * qy);
    const float R21 = 2.0f * (qy * qz + qw * qx);
    const float R22 = 1.0f - 2.0f * (qx * qx + qy * qy);

    const float s0 = expf(log_scales[3 * f + 0]);
    const float s1 = expf(log_scales[3 * f + 1]);
    const float s2 = expf(log_scales[3 * f + 2]);

    float G00, G10, G20, G01, G11, G21, G02, G12, G22;
    {
        float c0 = s0 * R00, c1 = s1 * R01, c2 = s2 * R02;
        G00 = ux * c0 + vx * c1 + wxv * c2;
        G10 = uy * c0 + vy * c1 + wyv * c2;
        G20 = uz * c0 + vz * c1 + wzv * c2;
    }
    {
        float c0 = s0 * R10, c1 = s1 * R11, c2 = s2 * R12;
        G01 = ux * c0 + vx * c1 + wxv * c2;
        G11 = uy * c0 + vy * c1 + wyv * c2;
        G21 = uz * c0 + vz * c1 + wzv * c2;
    }
    {
        float c0 = s0 * R20, c1 = s1 * R21, c2 = s2 * R22;
        G02 = ux * c0 + vx * c1 + wxv * c2;
        G12 = uy * c0 + vy * c1 + wyv * c2;
        G22 = uz * c0 + vz * c1 + wzv * c2;
    }

    const float gs0 = sqrtf(G00 * G00 + G10 * G10 + G20 * G20);
    const float gs1 = sqrtf(G01 * G01 + G11 * G11 + G21 * G21);
    const float gs2 = sqrtf(G02 * G02 + G12 * G12 + G22 * G22);
    const float rd0 = RCP(gs0 + EPSF), rd1 = RCP(gs1 + EPSF), rd2 = RCP(gs2 + EPSF);
    const float r00 = G00 * rd0, r10 = G10 * rd0, r20 = G20 * rd0;
    const float r01 = G01 * rd1, r11 = G11 * rd1, r21 = G21 * rd1;
    const float r02 = G02 * rd2, r12 = G12 * rd2, r22 = G22 * rd2;

    const float Qw = 0.5f * sqrtf(fmaxf(EPSF, 1.0f + r00 + r11 + r22));
    const float Qx = copysignf(0.5f * sqrtf(fmaxf(EPSF, 1.0f + r00 - r11 - r22)), r21 - r12);
    const float Qy = copysignf(0.5f * sqrtf(fmaxf(EPSF, 1.0f - r00 + r11 - r22)), r02 - r20);
    const float Qz = copysignf(0.5f * sqrtf(fmaxf(EPSF, 1.0f - r00 - r11 + r22)), r10 - r01);

    const float rqn2 = RCP(sqrtf(Qw * Qw + Qx * Qx + Qy * Qy + Qz * Qz) + EPSF);
    const float pw = Qw * rqn2, px = Qx * rqn2, py = Qy * rqn2, pz = Qz * rqn2;
    const float N00 = 1.0f - 2.0f * (py * py + pz * pz);
    const float N01 = 2.0f * (px * py - pw * pz);
    const float N02 = 2.0f * (px * pz + pw * py);
    const float N10 = 2.0f * (px * py + pw * pz);
    const float N11 = 1.0f - 2.0f * (px * px + pz * pz);
    const float N12 = 2.0f * (py * pz - pw * px);
    const float N20 = 2.0f * (px * pz - pw * py);
    const float N21 = 2.0f * (py * pz + pw * px);
    const float N22 = 1.0f - 2.0f * (px * px + py * py);

    const float M00 = N00 * gs0, M01 = N01 * gs1, M02 = N02 * gs2;
    const float M10 = N10 * gs0, M11 = N11 * gs1, M12 = N12 * gs2;
    const float M20 = N20 * gs0, M21 = N21 * gs1, M22 = N22 * gs2;
    const float C00 = M00 * M00 + M01 * M01 + M02 * M02;
    const float C01 = M00 * M10 + M01 * M11 + M02 * M12;
    const float C02 = M00 * M20 + M01 * M21 + M02 * M22;
    const float C11 = M10 * M10 + M11 * M11 + M12 * M12;
    const float C12 = M10 * M20 + M11 * M21 + M12 * M22;
    const float C22 = M20 * M20 + M21 * M21 + M22 * M22;

    const float valid = (tz > 0.2f) ? 1.0f : 0.0f;
    const float Zc = fmaxf(tz, 0.2f);           // sort key: exact
    const float rZc = RCP(Zc);
    const float mx = 200.0f * tx * rZc + 96.0f;
    const float my = 200.0f * ty * rZc + 96.0f;
    const float j00 = 200.0f * rZc;
    const float j02 = -200.0f * tx * (rZc * rZc);
    const float j11 = 200.0f * rZc;
    const float j12 = -200.0f * ty * (rZc * rZc);
    const float v00 = j00 * j00 * C00 + 2.0f * j00 * j02 * C02 + j02 * j02 * C22 + 0.3f;
    const float v01 = j00 * j11 * C01 + j00 * j12 * C02 + j02 * j11 * C12 + j02 * j12 * C22;
    const float v11 = j11 * j11 * C11 + 2.0f * j11 * j12 * C12 + j12 * j12 * C22 + 0.3f;
    const float rdet = RCP(fmaxf(v00 * v11 - v01 * v01, EPSF));
    const float conA = v11 * rdet, conB = -v01 * rdet, conC = v00 * rdet;
    const float opv = expf(log_opac[f]) * valid;

    const float LA = 0.5f * LOG2E * conA;
    const float LB = LOG2E * conB;
    const float LC = 0.5f * LOG2E * conC;
    const float t4 = fmaf(-LB, LB, 4.0f * LA * LC);
    const float reach2 = 140.0f * LA * RCP(fmaxf(t4, 1e-30f));

    union { __half2 h; float f; } c01u, cbo;
    c01u.h = __floats2half2_rn(colors[3 * f + 0], colors[3 * f + 1]);
    cbo.h  = __floats2half2_rn(colors[3 * f + 2], opv);

    sp[0][f] = mx;
    sp[1][f] = my;
    sp[2][f] = reach2;
    sp[3][f] = LA;
    sp[4][f] = LB;
    sp[5][f] = LC;
    sp[6][f] = c01u.f;
    sp[7][f] = cbo.f;

    // ---- bitonic argsort on packed u64 (proven R1 network) ----
    unsigned long long kv =
        ((unsigned long long)__float_as_uint(Zc) << 32) | (unsigned int)f;

    #pragma unroll
    for (int k = 2; k <= 64; k <<= 1)
        #pragma unroll
        for (int j = k >> 1; j > 0; j >>= 1) {
            const unsigned long long pk = __shfl_xor(kv, j, 64);
            const bool keep_min = (((f & k) == 0) == ((f & j) == 0));
            kv = ((pk < kv) == keep_min) ? pk : kv;
        }

    skv[f] = kv;
    __syncthreads();

    for (int k = 128; k <= F_CNT; k <<= 1) {
        for (int j = k >> 1; j >= 64; j >>= 1) {
            const int x = f ^ j;
            if (x > f) {
                const unsigned long long a  = skv[f];
                const unsigned long long bb = skv[x];
                const bool up = ((f & k) == 0);
                if (up ? (a > bb) : (a < bb)) { skv[f] = bb; skv[x] = a; }
            }
            __syncthreads();
        }
        kv = skv[f];
        #pragma unroll
        for (int j = 32; j > 0; j >>= 1) {
            const unsigned long long pk = __shfl_xor(kv, j, 64);
            const bool keep_min = (((f & k) == 0) == ((f & j) == 0));
            kv = ((pk < kv) == keep_min) ? pk : kv;
        }
        skv[f] = kv;
        __syncthreads();
    }

    // ---- gather-write sorted 32 B records ----
    const int src = (int)(skv[f] & 0xffffffffULL);
    float4* __restrict__ d4 = (float4*)params + 2 * f;
    d4[0] = make_float4(sp[0][src], sp[1][src], sp[2][src], sp[3][src]);
    d4[1] = make_float4(sp[4][src], sp[5][src], sp[6][src], sp[7][src]);
}

// ---------------------------------------------------------------- kernel 2
// 1024 blocks x 512 thr (4 blocks/CU, 8 waves/SIMD). Block b: quarter
// q = b>>8 owns segments [4q, 4q+4) (each 64 records); region
// r = (b + q*64) & 255 (co-resident blocks -> different regions).
// 8 waves = 4 local segs x 2 strips; per-wave 64-record stream,
// cull + hlist + blend exactly as R6 (body unchanged).
__global__ __launch_bounds__(512)
void render_partial_kernel(const float* __restrict__ params,
                           float* __restrict__ partials)
{
    __shared__ float4 lds4[512];           // 256 records x 2 float4 = 8 KB
    __shared__ float2 myr[256];            // (my, reach2) side table, 2 KB
    __shared__ unsigned int hlist[8][SEG_LEN];   // 2 KB

    const int tid  = threadIdx.x;
    const int lane = tid & 63;
    const int wv   = tid >> 6;             // 0..7

    const int bid = blockIdx.x;
    const int q   = bid >> 8;              // segment quarter 0..3
    const int r   = (bid + q * 64) & 255;  // pixel region

    // ---- stage this quarter's 256 records ----
    {
        const float4* __restrict__ rec4 = (const float4*)params;
        lds4[tid] = rec4[q * 512 + tid];
    }
    __syncthreads();
    if (tid < 256) {
        const float4 a = lds4[2 * tid];
        myr[tid] = make_float2(a.y, a.z);
    }
    __syncthreads();

    const int pb1 = r * HALF_PX;
    const int pb2 = HW / 2 + r * HALF_PX;
    const int seg_l  = wv & 3;
    const bool strip2 = (wv >= 4);
    const int pbase  = strip2 ? pb2 : pb1;

    const float ra = (float)(pbase / W_IMG);
    const float rb = (float)((pbase + HALF_PX - 1) / W_IMG);

    // ---- wave-parallel cull + order-preserving compaction ----
    int nhit;
    {
        const float2 t0 = myr[seg_l * 64 + lane];
        const float dm0 = fmaxf(0.0f, fmaxf(ra - t0.x, t0.x - rb));
        const bool h0 = dm0 * dm0 <= t0.y;
        const unsigned long long m0 = __ballot(h0);
        const unsigned long long lt = (1ULL << lane) - 1ULL;
        const int pos0 = __popcll(m0 & lt);
        if (h0) hlist[wv][pos0] = (unsigned)lane;
        nhit = __popcll(m0);
    }
    __syncthreads();

    const int p0 = pbase + lane, p1 = pbase + 64 + lane;
    const float fx0 = (float)(p0 % W_IMG), fy0 = (float)(p0 / W_IMG);
    const float fx1 = (float)(p1 % W_IMG), fy1 = (float)(p1 / W_IMG);

    float T0 = 1.0f, R0 = 0.0f, G0 = 0.0f, B0 = 0.0f;
    float T1 = 1.0f, R1 = 0.0f, G1 = 0.0f, B1 = 0.0f;

    const float4* __restrict__ Lb = lds4 + (seg_l << 7);   // seg_l*64 records
    for (int i = 0; i < nhit; ++i) {
        const int rr = (int)hlist[wv][i];
        const float4 a  = Lb[2 * rr + 0];
        const float4 bb = Lb[2 * rr + 1];
        const float my = a.y;
        const float LA = a.w, LB = bb.x, LC = bb.y;
        union { float f; __half2 h; } urg, ubo;
        urg.f = bb.z;  ubo.f = bb.w;
        const float2 crg = __half22float2(urg.h);
        const float2 cbo = __half22float2(ubo.h);
        const float  cb  = cbo.x, opv = cbo.y;

        {
            const float dx = fx0 - a.x, dy = fy0 - my;
            const float t  = fmaf(LB, dy, LA * dx);
            const float u2 = (LC * dy) * dy;
            const float n  = -fmaf(t, dx, u2);
            const float e2 = exp2f(fminf(n, 0.0f));
            const float al = fminf(opv * e2, 0.99f);
            const float w  = al * T0;
            R0 = fmaf(w, crg.x, R0); G0 = fmaf(w, crg.y, G0); B0 = fmaf(w, cb, B0);
            T0 -= w;
        }
        {
            const float dx = fx1 - a.x, dy = fy1 - my;
            const float t  = fmaf(LB, dy, LA * dx);
            const float u2 = (LC * dy) * dy;
            const float n  = -fmaf(t, dx, u2);
            const float e2 = exp2f(fminf(n, 0.0f));
            const float al = fminf(opv * e2, 0.99f);
            const float w  = al * T1;
            R1 = fmaf(w, crg.x, R1); G1 = fmaf(w, crg.y, G1); B1 = fmaf(w, cb, B1);
            T1 -= w;
        }
    }

    // ---- write per-(region, gseg) partials ----
    float4* __restrict__ part = (float4*)partials;
    const int gseg = 4 * q + seg_l;
    const int base = (r * N_SEG + gseg) * PIX_PER_BLK + (strip2 ? HALF_PX : 0);
    part[base + lane] = make_float4(R0, G0, B0, T0);
    if (lane < 8)
        part[base + 64 + lane] = make_float4(R1, G1, B1, T1);
}

// ---------------------------------------------------------------- kernel 3
// Fold the 16 segment partials per pixel, write image, reduce loss.
__global__ __launch_bounds__(256)
void combine_kernel(const float* __restrict__ partials,
                    const float* __restrict__ img,
                    const float* __restrict__ mask,
                    float* __restrict__ out)
{
    __shared__ float lossb[PIX_PER_BLK];

    const int tid = threadIdx.x;
    const int c   = blockIdx.x;
    const int pb1 = c * HALF_PX;
    const int pb2 = HW / 2 + c * HALF_PX;

    float lsum = 0.0f;
    if (tid < PIX_PER_BLK) {
        const float4* __restrict__ part = (const float4*)partials;
        float R = 0.0f, G = 0.0f, B = 0.0f, Tt = 1.0f;
        #pragma unroll
        for (int s = 0; s < N_SEG; ++s) {
            const float4 cc = part[(c * N_SEG + s) * PIX_PER_BLK + tid];
            R += Tt * cc.x; G += Tt * cc.y; B += Tt * cc.z;
            Tt *= cc.w;
        }
        const float bg = Tt;
        const float o0 = R + bg, o1 = G + bg, o2 = B + bg;
        const int p = (tid < HALF_PX) ? (pb1 + tid) : (pb2 + tid - HALF_PX);
        out[p]          = o0;
        out[HW + p]     = o1;
        out[2 * HW + p] = o2;

        const float m = mask[p];
        const float base = 1.0f - m;
        const float e0 = o0 - (base + img[p] * m);
        const float e1 = o1 - (base + img[HW + p] * m);
        const float e2 = o2 - (base + img[2 * HW + p] * m);
        lsum = e0 * e0 + e1 * e1 + e2 * e2;
    }

    if (tid < PIX_PER_BLK) lossb[tid] = lsum;
    __syncthreads();
    if (tid < 64) {
        float s = lossb[tid] + lossb[tid + 64] + (tid < 16 ? lossb[tid + 128] : 0.0f);
        #pragma unroll
        for (int off = 32; off > 0; off >>= 1) s += __shfl_down(s, off);
        if (tid == 0)
            atomicAdd(out + 3 * HW, s * (1.0f / (float)(3 * HW)));
    }
}

extern "C" void kernel_launch(void* const* d_in, const int* in_sizes, int n_in,
                              void* d_out, int out_size, void* d_ws, size_t ws_size,
                              hipStream_t stream)
{
    const float* img        = (const float*)d_in[0];
    const float* mask       = (const float*)d_in[1];
    const float* vp         = (const float*)d_in[2];
    const int*   faces      = (const int*)d_in[3];
    const float* rot_qs     = (const float*)d_in[4];
    const float* log_scales = (const float*)d_in[5];
    const float* colors     = (const float*)d_in[6];
    const float* log_opac   = (const float*)d_in[7];
    float* out      = (float*)d_out;
    float* params   = (float*)d_ws;                 // 32 KB records
    float* partials = (float*)d_ws + 8192;          // 9.4 MB partials

    prep_sort_kernel<<<1, F_CNT, 0, stream>>>(vp, faces, rot_qs, log_scales,
                                              colors, log_opac, params, out);
    render_partial_kernel<<<1024, 512, 0, stream>>>(params, partials);
    combine_kernel<<<256, 256, 0, stream>>>(partials, img, mask, out);
}